// Round 10
// baseline (183.981 us; speedup 1.0000x reference)
//
#include <hip/hip_runtime.h>

typedef __attribute__((ext_vector_type(8))) short bf16x8;
typedef __attribute__((ext_vector_type(4))) float f32x4;

__device__ __forceinline__ float bf2f(unsigned short u) {
    union { unsigned u; float f; } x; x.u = (unsigned)u << 16; return x.f;
}
__device__ __forceinline__ unsigned short f2bf(float f) {
    union { float f; unsigned u; } x; x.f = f;
    unsigned r = x.u + 0x7fffu + ((x.u >> 16) & 1u);
    return (unsigned short)(r >> 16);
}

#define GLDS(src, dst) __builtin_amdgcn_global_load_lds( \
    (const __attribute__((address_space(1))) void*)(src), \
    (__attribute__((address_space(3))) void*)(dst), 16, 0, 0)

// ---------------------------------------------------------------------------
// Weight prep (verified R9): 17 logical [256 n][256 k] bf16 matrices, stored
// FRAGMENT-TILED: matrix m at wt + m*65536, [t 0..15][kc 0..7][lane][e]
// with n = t*16 + (lane&15), k = kc*32 + (lane>>4)*8 + e.
// m0=W1(k<128), m1-4=wceff(n<96, conv-folded), m5-8=Wcat(k<96), m9-12=Wf1,
// m13-16=Wf2. bceff [4][256] f32 appended.
// ---------------------------------------------------------------------------
__global__ __launch_bounds__(256) void prep(
    const float* __restrict__ filters,
    const float* __restrict__ Wc1, const float* __restrict__ Wc2, const float* __restrict__ Wc3,
    const float* __restrict__ bc1, const float* __restrict__ bc2, const float* __restrict__ bc3,
    const float* __restrict__ W1, const float* __restrict__ Wcat,
    const float* __restrict__ Wf1, const float* __restrict__ Wf2,
    unsigned short* __restrict__ wt, float* __restrict__ bceff)
{
    int idx = blockIdx.x * 256 + threadIdx.x;
    if (idx < 1114112) {
        const int m    = idx >> 16;          // 0..16
        const int j    = idx & 65535;
        const int t    = j >> 12;
        const int kc   = (j >> 9) & 7;
        const int lane = (j >> 3) & 63;
        const int e    = j & 7;
        const int n = t * 16 + (lane & 15);
        const int k = kc * 32 + (lane >> 4) * 8 + e;
        float v = 0.f;
        if (m == 0) {
            if (k < 128) v = W1[n * 128 + k];
        } else if (m <= 4) {
            if (n < 96) {
                const int it = m - 1, c = n >> 5, jj = n & 31;
                const float* Wc = (c == 0) ? Wc1 : (c == 1) ? Wc2 : Wc3;
                const float* f  = filters + c * 25;
                float acc = 0.f;
                #pragma unroll
                for (int q = 0; q < 25; ++q) {
                    int hh = k + 12 - q;
                    if (hh >= 0 && hh < 256) acc += f[q] * Wc[(it * 32 + jj) * 256 + hh];
                }
                v = acc;
            }
        } else if (m <= 8) {
            const int it = m - 5;
            if (k < 96) v = Wcat[(it * 256 + n) * 96 + k];
        } else if (m <= 12) {
            const int it = m - 9;
            v = Wf1[(it * 256 + n) * 256 + k];
        } else {
            const int it = m - 13;
            v = Wf2[(it * 256 + n) * 256 + k];
        }
        wt[idx] = f2bf(v);
    } else if (idx < 1115136) {
        const int j = idx - 1114112;         // [4][256]
        const int it = j >> 8, n = j & 255;
        float v = 0.f;
        if (n < 96) {
            const int c = n >> 5, jj = n & 31;
            const float* bc = (c == 0) ? bc1 : (c == 1) ? bc2 : bc3;
            v = bc[it * 32 + jj];
        }
        bceff[j] = v;
    }
}

// ---------------------------------------------------------------------------
// Persistent mega-kernel: 512 blocks x 256 threads (4 waves: 2 wm x 2 wn),
// 64 rows/block, 80KB LDS -> 2 blocks/CU (two independent barrier groups
// per CU hide each other's stalls). Rolled 17-stage loop.
// acc = mfma(W_frag, act_frag): D col(lane&15)=row m, D row(hi*4+reg)=chan n.
// LDS: act 32KB + tmp 32KB + wstg 16KB (epilogue overlays lnred/dotp on wstg).
// ---------------------------------------------------------------------------
__global__ __launch_bounds__(256, 2) void mega(
    const float* __restrict__ x,
    const unsigned short* __restrict__ wt, const float* __restrict__ bceff,
    const float* __restrict__ b1,
    const float* __restrict__ a0p, const float* __restrict__ g0, const float* __restrict__ be0,
    const float* __restrict__ bcat, const float* __restrict__ g1, const float* __restrict__ be1,
    const float* __restrict__ bf1, const float* __restrict__ af,
    const float* __restrict__ bf2, const float* __restrict__ g2, const float* __restrict__ be2,
    const float* __restrict__ Wout, const float* __restrict__ boutp,
    float* __restrict__ outg)
{
    __shared__ __align__(16) unsigned short actb[16384];  // 32KB [4 mt][8 kc][512]
    __shared__ __align__(16) unsigned short tmpb[16384];  // 32KB
    __shared__ __align__(16) unsigned short wstg[8192];   // 16KB [16 t][512]

    const int tid  = threadIdx.x;
    const int lane = tid & 63;
    const int wave = tid >> 6;          // 0..3
    const int wm   = wave >> 1;         // 0..1 (32 rows each)
    const int wn   = wave & 1;          // 0..1 (half the cols each)
    const int l15  = lane & 15;
    const int hi   = lane >> 4;
    const int rowbase = blockIdx.x * 64;

    // phase 0: stage x (f32) -> actb fragment tiles (bf16), 64 rows, K=128
    {
        const int r = tid >> 2, q = tid & 3;
        const float* xp = x + (size_t)(rowbase + r) * 128 + q * 32;
        #pragma unroll
        for (int gi = 0; gi < 8; ++gi) {
            const float4 xv = *(const float4*)(xp + gi * 4);
            const int j = q * 32 + gi * 4;
            const ushort4 o = {f2bf(xv.x), f2bf(xv.y), f2bf(xv.z), f2bf(xv.w)};
            *(ushort4*)&actb[((r >> 4) * 8 + (j >> 5)) * 512
                        + ((r & 15) + ((j >> 3) & 3) * 16) * 8 + (j & 7)] = o;
        }
        __syncthreads();
    }

    for (int s = 0; s < 17; ++s) {
        // ---- decode stage (wave-uniform) ----
        const int phase = (s == 0) ? 0 : ((s - 1) & 3) + 1;
        const int it    = (s == 0) ? 0 : (s - 1) >> 2;
        int wmidx, nkc, ntw, actmode, fdot = 0, hasres = 0;
        const unsigned short* in;
        unsigned short* out;
        const float *bias, *g = nullptr, *be = nullptr, *alphap = nullptr;
        switch (phase) {
          case 0: wmidx = 0; bias = b1; in = actb; out = actb;
                  nkc = 4; ntw = 8; actmode = 1; alphap = a0p; g = g0; be = be0; break;
          case 1: wmidx = 1 + it; bias = bceff + it * 256; in = actb; out = tmpb;
                  nkc = 8; ntw = 4; actmode = 2; break;
          case 2: wmidx = 5 + it; bias = bcat + it * 256; in = tmpb; out = actb;
                  nkc = 4; ntw = 8; actmode = 0; hasres = 1;
                  g = g1 + it * 256; be = be1 + it * 256; break;
          case 3: wmidx = 9 + it; bias = bf1 + it * 256; in = actb; out = tmpb;
                  nkc = 8; ntw = 8; actmode = 1; alphap = af + it; break;
          default: wmidx = 13 + it; bias = bf2 + it * 256; in = tmpb; out = actb;
                  nkc = 8; ntw = 8; actmode = 0; hasres = 1;
                  g = g2 + it * 256; be = be2 + it * 256;
                  fdot = (s == 16); break;
        }
        const unsigned short* Wg = wt + (size_t)wmidx * 65536;
        const int tpw = ntw >> 1;   // W tiles staged per wave (4 or 2)

        f32x4 acc[2][8];
        #pragma unroll
        for (int mt = 0; mt < 2; ++mt)
            #pragma unroll
            for (int nt = 0; nt < 8; ++nt) acc[mt][nt] = (f32x4){0.f, 0.f, 0.f, 0.f};

        for (int kc = 0; kc < nkc; ++kc) {
            __syncthreads();   // prev chunk fully consumed -> wstg writable
            #pragma unroll
            for (int tt = 0; tt < 4; ++tt)
                if (tt < tpw) {
                    const int t = wave * tpw + tt;
                    GLDS(Wg + (size_t)(t * 8 + kc) * 512 + lane * 8, &wstg[t * 512]);
                }
            __syncthreads();   // vmcnt(0)+barrier: all W landed
            const bf16x8 af0 = *(const bf16x8*)&in[((wm * 2 + 0) * 8 + kc) * 512 + lane * 8];
            const bf16x8 af1 = *(const bf16x8*)&in[((wm * 2 + 1) * 8 + kc) * 512 + lane * 8];
            #pragma unroll
            for (int nt = 0; nt < 8; ++nt)
                if (nt < ntw) {
                    const bf16x8 wf = *(const bf16x8*)&wstg[(wn * ntw + nt) * 512 + lane * 8];
                    acc[0][nt] = __builtin_amdgcn_mfma_f32_16x16x32_bf16(wf, af0, acc[0][nt], 0, 0, 0);
                    acc[1][nt] = __builtin_amdgcn_mfma_f32_16x16x32_bf16(wf, af1, acc[1][nt], 0, 0, 0);
                }
        }
        __syncthreads();   // all W reads done: wstg reusable as lnred/dotp

        // ---- epilogue: bias -> act -> res -> (LN) -> store/dot ----
        float* lnred = (float*)wstg;          // 256 f32 (64 rows x 2 wn x {s,q})
        float* dotp  = (float*)wstg + 256;    // 128 f32
        const float alpha = alphap ? alphap[0] : 0.1f;
        float vv[2][8][4];
        #pragma unroll
        for (int mt = 0; mt < 2; ++mt) {
            #pragma unroll
            for (int nt = 0; nt < 8; ++nt)
                if (nt < ntw) {
                    const int nb = wn * (ntw * 16) + nt * 16 + hi * 4;
                    const float4 bs = *(const float4*)(bias + nb);
                    float u0 = acc[mt][nt][0] + bs.x;
                    float u1 = acc[mt][nt][1] + bs.y;
                    float u2 = acc[mt][nt][2] + bs.z;
                    float u3 = acc[mt][nt][3] + bs.w;
                    if (actmode) {
                        u0 = u0 >= 0.f ? u0 : alpha * u0;
                        u1 = u1 >= 0.f ? u1 : alpha * u1;
                        u2 = u2 >= 0.f ? u2 : alpha * u2;
                        u3 = u3 >= 0.f ? u3 : alpha * u3;
                    }
                    if (hasres) {
                        const int ro = ((wm * 2 + mt) * 8 + (nb >> 5)) * 512
                                     + (l15 + ((nb >> 3) & 3) * 16) * 8 + (nb & 7);
                        const ushort4 rv = *(const ushort4*)&actb[ro];
                        u0 += bf2f(rv.x); u1 += bf2f(rv.y); u2 += bf2f(rv.z); u3 += bf2f(rv.w);
                    }
                    vv[mt][nt][0] = u0; vv[mt][nt][1] = u1;
                    vv[mt][nt][2] = u2; vv[mt][nt][3] = u3;
                }
        }

        float mean[2], rstd[2];
        if (g) {
            #pragma unroll
            for (int mt = 0; mt < 2; ++mt) {
                float sm = 0.f, q = 0.f;
                #pragma unroll
                for (int nt = 0; nt < 8; ++nt) {
                    #pragma unroll
                    for (int r = 0; r < 4; ++r) { const float v = vv[mt][nt][r]; sm += v; q += v * v; }
                }
                sm += __shfl_xor(sm, 16); sm += __shfl_xor(sm, 32);
                q  += __shfl_xor(q, 16);  q  += __shfl_xor(q, 32);
                if (hi == 0)
                    *(float2*)(lnred + (wm * 32 + mt * 16 + l15) * 4 + wn * 2) = make_float2(sm, q);
            }
            __syncthreads();
            #pragma unroll
            for (int mt = 0; mt < 2; ++mt) {
                const int m = wm * 32 + mt * 16 + l15;
                const float4 p = *(const float4*)(lnred + m * 4);   // s0,q0,s1,q1
                const float sm = p.x + p.z;
                const float q  = p.y + p.w;
                const float mu = sm * (1.f / 256.f);
                mean[mt] = mu;
                rstd[mt] = rsqrtf(q * (1.f / 256.f) - mu * mu + 1e-5f);
            }
        }

        #pragma unroll
        for (int mt = 0; mt < 2; ++mt) {
            float dp = 0.f;
            #pragma unroll
            for (int nt = 0; nt < 8; ++nt)
                if (nt < ntw) {
                    const int nb = wn * (ntw * 16) + nt * 16 + hi * 4;
                    float o0 = vv[mt][nt][0], o1 = vv[mt][nt][1];
                    float o2 = vv[mt][nt][2], o3 = vv[mt][nt][3];
                    if (g) {
                        const float4 gv = *(const float4*)(g + nb);
                        const float4 bv = *(const float4*)(be + nb);
                        o0 = (o0 - mean[mt]) * rstd[mt] * gv.x + bv.x;
                        o1 = (o1 - mean[mt]) * rstd[mt] * gv.y + bv.y;
                        o2 = (o2 - mean[mt]) * rstd[mt] * gv.z + bv.z;
                        o3 = (o3 - mean[mt]) * rstd[mt] * gv.w + bv.w;
                    }
                    if (!fdot) {
                        const ushort4 ov = {f2bf(o0), f2bf(o1), f2bf(o2), f2bf(o3)};
                        *(ushort4*)&out[((wm * 2 + mt) * 8 + (nb >> 5)) * 512
                                    + (l15 + ((nb >> 3) & 3) * 16) * 8 + (nb & 7)] = ov;
                    } else {
                        const float4 wv = *(const float4*)(Wout + nb);
                        dp += o0 * wv.x + o1 * wv.y + o2 * wv.z + o3 * wv.w;
                    }
                }
            if (fdot) {
                dp += __shfl_xor(dp, 16); dp += __shfl_xor(dp, 32);
                if (hi == 0) dotp[(wm * 32 + mt * 16 + l15) * 2 + wn] = dp;
            }
        }
        if (fdot) {
            __syncthreads();
            if (tid < 64) {
                const float2 pp = *(const float2*)(dotp + tid * 2);
                outg[rowbase + tid] = pp.x + pp.y + boutp[0];
            }
        }
        __syncthreads();   // stage-end: stores visible to all waves
    }
}

extern "C" void kernel_launch(void* const* d_in, const int* in_sizes, int n_in,
                              void* d_out, int out_size, void* d_ws, size_t ws_size,
                              hipStream_t stream)
{
    const float* x       = (const float*)d_in[0];
    const float* filters = (const float*)d_in[1];
    const float* W1      = (const float*)d_in[2];
    const float* b1      = (const float*)d_in[3];
    const float* a0      = (const float*)d_in[4];
    const float* g0      = (const float*)d_in[5];
    const float* be0     = (const float*)d_in[6];
    const float* Wc1     = (const float*)d_in[7];
    const float* bc1     = (const float*)d_in[8];
    const float* Wc2     = (const float*)d_in[9];
    const float* bc2     = (const float*)d_in[10];
    const float* Wc3     = (const float*)d_in[11];
    const float* bc3     = (const float*)d_in[12];
    const float* Wcat    = (const float*)d_in[13];
    const float* bcat    = (const float*)d_in[14];
    const float* g1      = (const float*)d_in[15];
    const float* be1     = (const float*)d_in[16];
    const float* Wf1     = (const float*)d_in[17];
    const float* bf1     = (const float*)d_in[18];
    const float* af      = (const float*)d_in[19];
    const float* Wf2     = (const float*)d_in[20];
    const float* bf2     = (const float*)d_in[21];
    const float* g2      = (const float*)d_in[22];
    const float* be2     = (const float*)d_in[23];
    const float* Wout    = (const float*)d_in[24];
    const float* boutp   = (const float*)d_in[25];
    float* outf = (float*)d_out;

    unsigned short* wt    = (unsigned short*)d_ws;          // 17*65536 shorts
    float*          bceff = (float*)(wt + 1114112);         // 1024 floats

    prep<<<dim3(4357), dim3(256), 0, stream>>>(
        filters, Wc1, Wc2, Wc3, bc1, bc2, bc3, W1, Wcat, Wf1, Wf2, wt, bceff);

    mega<<<dim3(512), dim3(256), 0, stream>>>(
        x, wt, bceff, b1, a0, g0, be0, bcat, g1, be1,
        bf1, af, bf2, g2, be2, Wout, boutp, outf);
}